// Round 1
// baseline (65.946 us; speedup 1.0000x reference)
//
#include <hip/hip_runtime.h>

// Regression_55791625175653
// ref: only c3 used. upsample4(nearest) -> 4^3 ones box conv (SAME, lo=1 hi=2)
//      -> softmax over D(192) -> sum(w * arange(192)) -> out [1,256,512] f32.
//
// Separable coarse-cell form: per axis, output phase p touches <=2 coarse
// cells with weights  p=0:(j-1,j)*(1,3)  p=1:(j)*(4)  p=2:(j,j+1)*(3,1)
// p=3:(j,j+1)*(2,2);  OOB cells contribute 0 (zero padding).

#define DC 48
#define HC 64
#define WC 128
#define WOUT 512
#define NOUT (256 * 512)

__device__ __forceinline__ void axis_weights(int p, int& off, float& w0, float& w1) {
    // p=0: off=-1,(1,3); p=1: off=0,(4,0); p=2: off=0,(3,1); p=3: off=0,(2,2)
    off = (p == 0) ? -1 : 0;
    w0  = (p == 0) ? 1.f : (p == 1) ? 4.f : (p == 2) ? 3.f : 2.f;
    w1  = (p == 0) ? 3.f : (p == 1) ? 0.f : (p == 2) ? 1.f : 2.f;
}

__global__ __launch_bounds__(256)
void regress_kernel(const float* __restrict__ c3, float* __restrict__ out) {
    int t = blockIdx.x * blockDim.x + threadIdx.x;   // 131072 threads
    int w = t & (WOUT - 1);
    int h = t >> 9;

    int jh = h >> 2, ph = h & 3;
    int jw = w >> 2, pw = w & 3;

    int offh, offw;
    float whA, whB, wwA, wwB;
    axis_weights(ph, offh, whA, whB);
    axis_weights(pw, offw, wwA, wwB);

    int jh0 = jh + offh, jh1 = jh0 + 1;
    float wh0 = (jh0 >= 0 && jh0 < HC) ? whA : 0.f;
    float wh1 = (jh1 < HC) ? whB : 0.f;          // jh1 >= 0 always
    jh0 = (jh0 < 0) ? 0 : jh0;
    jh1 = (jh1 > HC - 1) ? HC - 1 : jh1;

    int jw0 = jw + offw, jw1 = jw0 + 1;
    float ww0 = (jw0 >= 0 && jw0 < WC) ? wwA : 0.f;
    float ww1 = (jw1 < WC) ? wwB : 0.f;
    jw0 = (jw0 < 0) ? 0 : jw0;
    jw1 = (jw1 > WC - 1) ? WC - 1 : jw1;

    float w00 = wh0 * ww0, w01 = wh0 * ww1, w10 = wh1 * ww0, w11 = wh1 * ww1;

    int i00 = jh0 * WC + jw0, i01 = jh0 * WC + jw1;
    int i10 = jh1 * WC + jw0, i11 = jh1 * WC + jw1;

    // coarse-D profile, combined over (h,w) — stays in VGPRs (full unroll,
    // compile-time indices only)
    float S[DC];
    #pragma unroll
    for (int jd = 0; jd < DC; ++jd) {
        const float* p = c3 + jd * (HC * WC);
        S[jd] = w00 * p[i00] + w01 * p[i01] + w10 * p[i10] + w11 * p[i11];
    }

    // pass 1: max over the 192 conv values
    float m = -1e30f;
    #pragma unroll
    for (int jd = 0; jd < DC; ++jd) {
        float Sm = (jd == 0) ? 0.f : S[jd - 1];
        float Sc = S[jd];
        float Sp = (jd == DC - 1) ? 0.f : S[jd + 1];
        float x0 = Sm + 3.f * Sc;        // d = 4jd+0
        float x1 = 4.f * Sc;             // d = 4jd+1
        float x2 = 3.f * Sc + Sp;        // d = 4jd+2
        float x3 = 2.f * Sc + 2.f * Sp;  // d = 4jd+3
        m = fmaxf(m, fmaxf(fmaxf(x0, x1), fmaxf(x2, x3)));
    }

    // pass 2: softmax accumulation + weighted index
    float s = 0.f, sd = 0.f;
    #pragma unroll
    for (int jd = 0; jd < DC; ++jd) {
        float Sm = (jd == 0) ? 0.f : S[jd - 1];
        float Sc = S[jd];
        float Sp = (jd == DC - 1) ? 0.f : S[jd + 1];
        float x0 = Sm + 3.f * Sc;
        float x1 = 4.f * Sc;
        float x2 = 3.f * Sc + Sp;
        float x3 = 2.f * Sc + 2.f * Sp;
        float e0 = __expf(x0 - m);
        float e1 = __expf(x1 - m);
        float e2 = __expf(x2 - m);
        float e3 = __expf(x3 - m);
        s += e0 + e1 + e2 + e3;
        float d0 = (float)(4 * jd);
        sd = fmaf(e0, d0, sd);
        sd = fmaf(e1, d0 + 1.f, sd);
        sd = fmaf(e2, d0 + 2.f, sd);
        sd = fmaf(e3, d0 + 3.f, sd);
    }

    out[t] = sd / s;
}

extern "C" void kernel_launch(void* const* d_in, const int* in_sizes, int n_in,
                              void* d_out, int out_size, void* d_ws, size_t ws_size,
                              hipStream_t stream) {
    (void)in_sizes; (void)n_in; (void)d_ws; (void)ws_size; (void)out_size;
    const float* c3 = (const float*)d_in[2];   // only c3 is used (inference path)
    float* out = (float*)d_out;
    regress_kernel<<<NOUT / 256, 256, 0, stream>>>(c3, out);
}